// Round 7
// baseline (227.656 us; speedup 1.0000x reference)
//
#include <hip/hip_runtime.h>
#include <hip/hip_bf16.h>

#define N_NODES 50000
#define N_EDGES 800000
#define EMB 100
#define HALF_EMB 50
#define ROW_U4 16                      // uint4 per padded row (128 bf16, 256B = 4 cachelines)
#define ROW_B2 64                      // bf162 per padded row
#define NORM_EPS 1e-12f
#define BROWS 128                      // rows per bucket
#define NB ((N_NODES + BROWS - 1) / BROWS)   // 391 buckets
#define CAP 4096                       // slab capacity per bucket (avg fill ~2046)
#define EPB 4096                       // edges per partition block -> run len ~10.5
#define SCAT_BLOCKS ((N_EDGES + EPB - 1) / EPB)   // 196
#define CONV_BLOCKS 3125               // 16 waves x 3125 = 50000 nodes exactly

// Dispatch A (merged): blocks [0,196) = bucket scatter (1024 thr, 16 waves for
// latency hiding); blocks [196, 196+3125) = conv_emb. Disjoint inputs -> the
// conv blocks use the CUs scatter leaves idle.
__global__ __launch_bounds__(1024) void scatter_conv(
        const int* __restrict__ adj_row, const int* __restrict__ adj_col,
        const float* __restrict__ adj_val, int* __restrict__ bucket_cnt,
        int2* __restrict__ slab,
        const float* __restrict__ emb, float* __restrict__ norm0,
        __hip_bfloat162* __restrict__ xb) {
    const int t = threadIdx.x;
    if (blockIdx.x >= SCAT_BLOCKS) {
        // ---- conv_emb: one wave per node, writes 256B padded bf16 row ----
        int wave = (blockIdx.x - SCAT_BLOCKS) * 16 + (t >> 6);
        int lane = t & 63;
        if (wave >= N_NODES) return;
        float2 v = make_float2(0.0f, 0.0f);
        if (lane < HALF_EMB) v = ((const float2*)emb)[(size_t)wave * HALF_EMB + lane];
        float s = v.x * v.x + v.y * v.y;
        #pragma unroll
        for (int off = 32; off > 0; off >>= 1) s += __shfl_xor(s, off);
        if (lane == 0) norm0[wave] = sqrtf(s);
        __hip_bfloat162 b;
        b.x = __float2bfloat16(v.x);     // lanes >= 50 write exact zeros (pad)
        b.y = __float2bfloat16(v.y);
        xb[(size_t)wave * ROW_B2 + lane] = b;   // all 64 lanes: 256B coalesced
        return;
    }
    // ---- bucket scatter ----
    __shared__ int hist[NB];
    __shared__ int cur[NB];
    const int base_e = blockIdx.x * EPB;
    for (int i = t; i < NB; i += 1024) hist[i] = 0;
    __syncthreads();
    int rows[EPB / 1024];
    #pragma unroll
    for (int j = 0; j < EPB / 1024; ++j) {
        int e = base_e + j * 1024 + t;
        int r = (e < N_EDGES) ? adj_row[e] : -1;
        rows[j] = r;
        if (r >= 0) atomicAdd(&hist[r >> 7], 1);
    }
    __syncthreads();
    for (int i = t; i < NB; i += 1024) {
        int c = hist[i];
        cur[i] = (c > 0) ? atomicAdd(&bucket_cnt[i], c) : 0;
    }
    __syncthreads();
    #pragma unroll
    for (int j = 0; j < EPB / 1024; ++j) {
        int e = base_e + j * 1024 + t;
        int r = rows[j];
        if (r >= 0) {
            int b = r >> 7;
            int p = atomicAdd(&cur[b], 1);
            unsigned rc = ((unsigned)r << 16) | (unsigned)adj_col[e];
            slab[(size_t)b * CAP + p] = make_int2((int)rc, __float_as_int(adj_val[e]));
        }
    }
}

// Dispatch B: per-bucket counting sort (1024 thr) -> compressed CSR + row_ptr.
__global__ __launch_bounds__(1024) void csr_build(
        const int* __restrict__ bucket_cnt, const int2* __restrict__ slab,
        unsigned* __restrict__ csr4, int* __restrict__ row_ptr) {
    __shared__ int2 eds[CAP];
    __shared__ int hist[BROWS];   // later reused as scatter cursor
    __shared__ int incl[BROWS];
    __shared__ int red[1024];
    const int b = blockIdx.x, t = threadIdx.x;
    // embedded exclusive prefix: base = sum_{i<b} cnt[i]  (b < 391 < 1024)
    red[t] = (t < b) ? bucket_cnt[t] : 0;
    __syncthreads();
    #pragma unroll
    for (int off = 512; off > 0; off >>= 1) {
        if (t < off) red[t] += red[t + off];
        __syncthreads();
    }
    const int base = red[0];
    const int cnt = bucket_cnt[b];
    for (int i = t; i < cnt; i += 1024) eds[i] = slab[(size_t)b * CAP + i];
    if (t < BROWS) hist[t] = 0;
    __syncthreads();
    for (int i = t; i < cnt; i += 1024)
        atomicAdd(&hist[(int)(((unsigned)eds[i].x) >> 16) & (BROWS - 1)], 1);
    __syncthreads();
    int v = (t < BROWS) ? hist[t] : 0;
    if (t < BROWS) incl[t] = v;
    __syncthreads();
    #pragma unroll
    for (int off = 1; off < BROWS; off <<= 1) {
        int n = (t >= off && t < BROWS) ? incl[t - off] : 0;
        __syncthreads();
        if (t < BROWS) incl[t] += n;
        __syncthreads();
    }
    int ex = (t < BROWS) ? (incl[t] - v) : 0;
    __syncthreads();
    if (t < BROWS) hist[t] = ex;          // cursor init
    int gr = b * BROWS + t;
    if (t < BROWS && gr < N_NODES) row_ptr[gr] = base + ex;
    if (b == 0 && t == 0) row_ptr[N_NODES] = N_EDGES;
    __syncthreads();
    for (int i = t; i < cnt; i += 1024) {
        int2 e = eds[i];
        int l = (int)(((unsigned)e.x) >> 16) & (BROWS - 1);
        int p = atomicAdd(&hist[l], 1);
        unsigned col = (unsigned)e.x & 0xFFFFu;
        __hip_bfloat16 hv = __float2bfloat16(__int_as_float(e.y));
        unsigned vb = (unsigned)*reinterpret_cast<unsigned short*>(&hv);
        csr4[base + p] = (col << 16) | vb;
    }
}

// unpack 8 bf16 (uint4) -> 2x float4, bit-twiddle only
__device__ inline void up8(uint4 u, float4& lo, float4& hi) {
    lo.x = __uint_as_float(u.x << 16);
    lo.y = __uint_as_float(u.x & 0xFFFF0000u);
    lo.z = __uint_as_float(u.y << 16);
    lo.w = __uint_as_float(u.y & 0xFFFF0000u);
    hi.x = __uint_as_float(u.z << 16);
    hi.y = __uint_as_float(u.z & 0xFFFF0000u);
    hi.z = __uint_as_float(u.w << 16);
    hi.w = __uint_as_float(u.w & 0xFFFF0000u);
}

__device__ inline unsigned pack2(float a, float b) {
    __hip_bfloat16 x = __float2bfloat16(a), y = __float2bfloat16(b);
    return (unsigned)*(unsigned short*)&x | ((unsigned)*(unsigned short*)&y << 16);
}

// FMA one edge (record r, half-row data u) into the accumulators
__device__ inline void fma_edge(unsigned r, uint4 u, float4& accL, float4& accH) {
    float v = __uint_as_float(r << 16);
    float4 l, h;
    up8(u, l, h);
    accL.x += v * l.x; accL.y += v * l.y; accL.z += v * l.z; accL.w += v * l.w;
    accH.x += v * h.x; accH.y += v * h.y; accH.z += v * h.z; accH.w += v * h.w;
}

// SpMM, feature-half phased: per wave, process all edges twice -- phase h
// gathers only the 128B half h of each source row. Working set per phase is
// 6.4MB (vs 12.8MB) -> higher per-XCD L2 hit rate, less L3 traffic.
// Layout per phase: 8 edge-slots x 8 lanes. Slot g = lane>>3 owns edge d+g;
// lane (g,c) loads uint4 = 8 bf16 features (u4 index h*8+c) of its edge's
// source row. Same instruction count and bytes as the full-row layout.
// rec = col<<16 | bf16(val). Pad recs = 0 => val 0 (safe).
__global__ void spmm_fused(const int* __restrict__ row_ptr,
                           const unsigned* __restrict__ csr4,
                           const uint4* __restrict__ xb,
                           uint4* __restrict__ yb,
                           float* __restrict__ norm_out,
                           const float* __restrict__ a,
                           const uint4* __restrict__ ep0,
                           const uint4* __restrict__ ep1,
                           const float* __restrict__ norms,
                           float* __restrict__ out,
                           int final_layer) {
    int wave = blockIdx.x * (blockDim.x >> 6) + (threadIdx.x >> 6);
    int lane = threadIdx.x & 63;
    if (wave >= N_NODES) return;
    int start = row_ptr[wave];
    int end   = row_ptr[wave + 1];
    int deg   = end - start;
    unsigned myrec = (lane < deg) ? csr4[start + lane] : 0u;
    int g = lane >> 3, c = lane & 7;
    int dn  = (deg < 64) ? deg : 64;
    int dn8 = (dn + 7) & ~7;           // round up to 8 (pad recs are 0)
    float4 accL0, accH0;               // saved phase-0 result (final layer)
    float s = 0.0f;
    #pragma unroll
    for (int h = 0; h < 2; ++h) {
        const uint4* xh = xb + h * 8;  // u4 base offset for this half
        float4 accL = make_float4(0.0f, 0.0f, 0.0f, 0.0f);
        float4 accH = make_float4(0.0f, 0.0f, 0.0f, 0.0f);
        int d = 0;
        for (; d + 16 <= dn8; d += 16) {   // 2 gathers in flight : 16 edges
            unsigned ra = __shfl(myrec, d + g);
            unsigned rb = __shfl(myrec, d + 8 + g);
            uint4 ua = xh[(size_t)(ra >> 16) * ROW_U4 + c];
            uint4 ub = xh[(size_t)(rb >> 16) * ROW_U4 + c];
            fma_edge(ra, ua, accL, accH);
            fma_edge(rb, ub, accL, accH);
        }
        if (d < dn8) {                     // at most one 8-edge chunk
            unsigned r = __shfl(myrec, d + g);
            uint4 u = xh[(size_t)(r >> 16) * ROW_U4 + c];
            fma_edge(r, u, accL, accH);
        }
        // overflow fallback (deg > 64): 8 edges per pass, slot g selects edge
        for (int e = start + 64; e < end; e += 8) {
            unsigned r = (e + g < end) ? csr4[e + g] : 0u;
            uint4 u = xh[(size_t)(r >> 16) * ROW_U4 + c];
            fma_edge(r, u, accL, accH);
        }
        // combine the 8 edge-slots: all slots end with full half-row sums
        accL.x += __shfl_xor(accL.x, 8); accL.x += __shfl_xor(accL.x, 16); accL.x += __shfl_xor(accL.x, 32);
        accL.y += __shfl_xor(accL.y, 8); accL.y += __shfl_xor(accL.y, 16); accL.y += __shfl_xor(accL.y, 32);
        accL.z += __shfl_xor(accL.z, 8); accL.z += __shfl_xor(accL.z, 16); accL.z += __shfl_xor(accL.z, 32);
        accL.w += __shfl_xor(accL.w, 8); accL.w += __shfl_xor(accL.w, 16); accL.w += __shfl_xor(accL.w, 32);
        accH.x += __shfl_xor(accH.x, 8); accH.x += __shfl_xor(accH.x, 16); accH.x += __shfl_xor(accH.x, 32);
        accH.y += __shfl_xor(accH.y, 8); accH.y += __shfl_xor(accH.y, 16); accH.y += __shfl_xor(accH.y, 32);
        accH.z += __shfl_xor(accH.z, 8); accH.z += __shfl_xor(accH.z, 16); accH.z += __shfl_xor(accH.z, 32);
        accH.w += __shfl_xor(accH.w, 8); accH.w += __shfl_xor(accH.w, 16); accH.w += __shfl_xor(accH.w, 32);
        // half-row sum of squares: reduce the 8 c-lanes (slots duplicate)
        float sh = accL.x * accL.x + accL.y * accL.y + accL.z * accL.z + accL.w * accL.w
                 + accH.x * accH.x + accH.y * accH.y + accH.z * accH.z + accH.w * accH.w;
        sh += __shfl_xor(sh, 1); sh += __shfl_xor(sh, 2); sh += __shfl_xor(sh, 4);
        s += sh;
        if (!final_layer) {
            if (g == 0) {              // 8 lanes write this 128B half
                uint4 o;
                o.x = pack2(accL.x, accL.y);
                o.y = pack2(accL.z, accL.w);
                o.z = pack2(accH.x, accH.y);
                o.w = pack2(accH.z, accH.w);
                yb[(size_t)wave * ROW_U4 + h * 8 + c] = o;
            }
        } else if (h == 0) {
            accL0 = accL; accH0 = accH;    // all lanes hold the duplicate
        } else {
            // epilogue: combine 4 normalized layers, write f32 out rows
            float s0 = a[0] / fmaxf(norms[wave], NORM_EPS);
            float s1 = a[1] / fmaxf(norms[N_NODES + wave], NORM_EPS);
            float s2 = a[2] / fmaxf(norms[2 * N_NODES + wave], NORM_EPS);
            float s3 = a[3] / fmaxf(sqrtf(s), NORM_EPS);
            float4* out4 = (float4*)out;
            size_t fb = (size_t)wave * 25;   // out rows are unpadded f32x100
            if (g == 0) {
                // half 0: u4 idx c in [0,8) -> out4[2c], out4[2c+1]
                size_t idx = (size_t)wave * ROW_U4 + c;
                float4 f0l, f0h, f1l, f1h, f2l, f2h;
                up8(ep0[idx], f0l, f0h);
                up8(ep1[idx], f1l, f1h);
                up8(xb[idx],  f2l, f2h);
                float4 o0, o1;
                o0.x = s0 * f0l.x + s1 * f1l.x + s2 * f2l.x + s3 * accL0.x;
                o0.y = s0 * f0l.y + s1 * f1l.y + s2 * f2l.y + s3 * accL0.y;
                o0.z = s0 * f0l.z + s1 * f1l.z + s2 * f2l.z + s3 * accL0.z;
                o0.w = s0 * f0l.w + s1 * f1l.w + s2 * f2l.w + s3 * accL0.w;
                o1.x = s0 * f0h.x + s1 * f1h.x + s2 * f2h.x + s3 * accH0.x;
                o1.y = s0 * f0h.y + s1 * f1h.y + s2 * f2h.y + s3 * accH0.y;
                o1.z = s0 * f0h.z + s1 * f1h.z + s2 * f2h.z + s3 * accH0.z;
                o1.w = s0 * f0h.w + s1 * f1h.w + s2 * f2h.w + s3 * accH0.w;
                out4[fb + 2 * c]     = o0;
                out4[fb + 2 * c + 1] = o1;
            } else if (g == 1 && c < 5) {
                // half 1: u4 idx 8+c in [8,13) -> out4[16+2c] (+1 if c<4)
                size_t idx = (size_t)wave * ROW_U4 + 8 + c;
                float4 f0l, f0h, f1l, f1h, f2l, f2h;
                up8(ep0[idx], f0l, f0h);
                up8(ep1[idx], f1l, f1h);
                up8(xb[idx],  f2l, f2h);
                float4 o0, o1;
                o0.x = s0 * f0l.x + s1 * f1l.x + s2 * f2l.x + s3 * accL.x;
                o0.y = s0 * f0l.y + s1 * f1l.y + s2 * f2l.y + s3 * accL.y;
                o0.z = s0 * f0l.z + s1 * f1l.z + s2 * f2l.z + s3 * accL.z;
                o0.w = s0 * f0l.w + s1 * f1l.w + s2 * f2l.w + s3 * accL.w;
                o1.x = s0 * f0h.x + s1 * f1h.x + s2 * f2h.x + s3 * accH.x;
                o1.y = s0 * f0h.y + s1 * f1h.y + s2 * f2h.y + s3 * accH.y;
                o1.z = s0 * f0h.z + s1 * f1h.z + s2 * f2h.z + s3 * accH.z;
                o1.w = s0 * f0h.w + s1 * f1h.w + s2 * f2h.w + s3 * accH.w;
                out4[fb + 16 + 2 * c] = o0;
                if (c < 4) out4[fb + 17 + 2 * c] = o1;  // c==4: feats 96..99 only
            }
        }
    }
    if (!final_layer && lane == 0) norm_out[wave] = sqrtf(s);
}

extern "C" void kernel_launch(void* const* d_in, const int* in_sizes, int n_in,
                              void* d_out, int out_size, void* d_ws, size_t ws_size,
                              hipStream_t stream) {
    const int*   adj_row   = (const int*)d_in[0];
    const int*   adj_col   = (const int*)d_in[1];
    const float* adj_val   = (const float*)d_in[2];
    const float* embedding = (const float*)d_in[3];
    const float* a         = (const float*)d_in[4];
    float* out = (float*)d_out;

    // workspace layout. xb2 overlays slab (slab dead after csr_build,
    // xb2 first written in layer-2 spmm -- stream-ordered, safe).
    // padded tables: 50000 * 16 uint4 = 12.8 MB each; slab = 12,812,288 B >= xb2.
    int2* slab     = (int2*)d_ws;                                  // 12.81 MB
    unsigned* csr4 = (unsigned*)(slab + (size_t)NB * CAP);         // 3.2 MB
    uint4* xbE = (uint4*)(csr4 + N_EDGES);                         // 12.8 MB
    uint4* xb1 = xbE + (size_t)N_NODES * ROW_U4;                   // 12.8 MB
    float* norms = (float*)(xb1 + (size_t)N_NODES * ROW_U4);       // 3*50,000
    int* row_ptr    = (int*)(norms + 3 * N_NODES);                 // 50,001
    int* bucket_cnt = row_ptr + (N_NODES + 1);                     // NB
    uint4* xb2 = (uint4*)slab;                                     // overlay

    const int node_blocks = (N_NODES + 3) / 4;          // 4 waves / block

    // ---- CSR build: (scatter || emb prep) -> per-bucket sort ----
    hipMemsetAsync(bucket_cnt, 0, sizeof(int) * NB, stream);
    scatter_conv<<<SCAT_BLOCKS + CONV_BLOCKS, 1024, 0, stream>>>(
        adj_row, adj_col, adj_val, bucket_cnt, slab,
        embedding, norms, (__hip_bfloat162*)xbE);
    csr_build<<<NB, 1024, 0, stream>>>(bucket_cnt, slab, csr4, row_ptr);

    // ---- layer 1, 2 (raw bf16 + norm), layer 3 (fused epilogue) ----
    spmm_fused<<<node_blocks, 256, 0, stream>>>(row_ptr, csr4, xbE,
                                                xb1, norms + N_NODES, a,
                                                nullptr, nullptr, nullptr,
                                                nullptr, 0);
    spmm_fused<<<node_blocks, 256, 0, stream>>>(row_ptr, csr4, xb1,
                                                xb2, norms + 2 * N_NODES, a,
                                                nullptr, nullptr, nullptr,
                                                nullptr, 0);
    spmm_fused<<<node_blocks, 256, 0, stream>>>(row_ptr, csr4, xb2,
                                                nullptr, nullptr, a,
                                                xbE, xb1, norms,
                                                out, 1);
}

// Round 8
// 203.008 us; speedup vs baseline: 1.1214x; 1.1214x over previous
//
#include <hip/hip_runtime.h>
#include <hip/hip_bf16.h>

#define N_NODES 50000
#define N_EDGES 800000
#define EMB 100
#define HALF_EMB 50
#define ROW_U4 16                      // uint4 per padded row (128 f16, 256B = 4 cachelines)
#define ROW_U1 64                      // u32 per padded row
#define NORM_EPS 1e-12f
#define BROWS 128                      // rows per bucket
#define NB ((N_NODES + BROWS - 1) / BROWS)   // 391 buckets
#define CAP 4096                       // slab capacity per bucket (avg fill ~2046)
#define EPB 4096                       // edges per partition block -> run len ~10.5
#define SCAT_BLOCKS ((N_EDGES + EPB - 1) / EPB)   // 196
#define CONV_BLOCKS 3125               // 16 waves x 3125 = 50000 nodes exactly

#define SEL_LO 0x01000504u             // v_perm: dst = (lo=src0.lo16, hi=src1.lo16)
#define SEL_HI 0x03020706u             // v_perm: dst = (lo=src0.hi16, hi=src1.hi16)

typedef _Float16 half2v __attribute__((ext_vector_type(2)));

__device__ inline unsigned pack2h(float a, float b) {
    unsigned short x = __builtin_bit_cast(unsigned short, (_Float16)a);
    unsigned short y = __builtin_bit_cast(unsigned short, (_Float16)b);
    return (unsigned)x | ((unsigned)y << 16);
}

// Dispatch A (merged): blocks [0,196) = bucket scatter (1024 thr, 16 waves for
// latency hiding); blocks [196, 196+3125) = conv_emb. Disjoint inputs -> the
// conv blocks use the CUs scatter leaves idle.
__global__ __launch_bounds__(1024) void scatter_conv(
        const int* __restrict__ adj_row, const int* __restrict__ adj_col,
        const float* __restrict__ adj_val, int* __restrict__ bucket_cnt,
        int2* __restrict__ slab,
        const float* __restrict__ emb, float* __restrict__ norm0,
        unsigned* __restrict__ xb) {
    const int t = threadIdx.x;
    if (blockIdx.x >= SCAT_BLOCKS) {
        // ---- conv_emb: one wave per node, writes 256B padded f16 row ----
        int wave = (blockIdx.x - SCAT_BLOCKS) * 16 + (t >> 6);
        int lane = t & 63;
        if (wave >= N_NODES) return;
        float2 v = make_float2(0.0f, 0.0f);
        if (lane < HALF_EMB) v = ((const float2*)emb)[(size_t)wave * HALF_EMB + lane];
        float s = v.x * v.x + v.y * v.y;
        #pragma unroll
        for (int off = 32; off > 0; off >>= 1) s += __shfl_xor(s, off);
        if (lane == 0) norm0[wave] = sqrtf(s);
        // lanes >= 50 write exact zeros (pad)
        xb[(size_t)wave * ROW_U1 + lane] = pack2h(v.x, v.y);
        return;
    }
    // ---- bucket scatter ----
    __shared__ int hist[NB];
    __shared__ int cur[NB];
    const int base_e = blockIdx.x * EPB;
    for (int i = t; i < NB; i += 1024) hist[i] = 0;
    __syncthreads();
    int rows[EPB / 1024];
    #pragma unroll
    for (int j = 0; j < EPB / 1024; ++j) {
        int e = base_e + j * 1024 + t;
        int r = (e < N_EDGES) ? adj_row[e] : -1;
        rows[j] = r;
        if (r >= 0) atomicAdd(&hist[r >> 7], 1);
    }
    __syncthreads();
    for (int i = t; i < NB; i += 1024) {
        int c = hist[i];
        cur[i] = (c > 0) ? atomicAdd(&bucket_cnt[i], c) : 0;
    }
    __syncthreads();
    #pragma unroll
    for (int j = 0; j < EPB / 1024; ++j) {
        int e = base_e + j * 1024 + t;
        int r = rows[j];
        if (r >= 0) {
            int b = r >> 7;
            int p = atomicAdd(&cur[b], 1);
            unsigned rc = ((unsigned)r << 16) | (unsigned)adj_col[e];
            slab[(size_t)b * CAP + p] = make_int2((int)rc, __float_as_int(adj_val[e]));
        }
    }
}

// Dispatch B: per-bucket counting sort (1024 thr) -> compressed CSR + row_ptr.
__global__ __launch_bounds__(1024) void csr_build(
        const int* __restrict__ bucket_cnt, const int2* __restrict__ slab,
        unsigned* __restrict__ csr4, int* __restrict__ row_ptr) {
    __shared__ int2 eds[CAP];
    __shared__ int hist[BROWS];   // later reused as scatter cursor
    __shared__ int incl[BROWS];
    __shared__ int red[1024];
    const int b = blockIdx.x, t = threadIdx.x;
    // embedded exclusive prefix: base = sum_{i<b} cnt[i]  (b < 391 < 1024)
    red[t] = (t < b) ? bucket_cnt[t] : 0;
    __syncthreads();
    #pragma unroll
    for (int off = 512; off > 0; off >>= 1) {
        if (t < off) red[t] += red[t + off];
        __syncthreads();
    }
    const int base = red[0];
    const int cnt = bucket_cnt[b];
    for (int i = t; i < cnt; i += 1024) eds[i] = slab[(size_t)b * CAP + i];
    if (t < BROWS) hist[t] = 0;
    __syncthreads();
    for (int i = t; i < cnt; i += 1024)
        atomicAdd(&hist[(int)(((unsigned)eds[i].x) >> 16) & (BROWS - 1)], 1);
    __syncthreads();
    int v = (t < BROWS) ? hist[t] : 0;
    if (t < BROWS) incl[t] = v;
    __syncthreads();
    #pragma unroll
    for (int off = 1; off < BROWS; off <<= 1) {
        int n = (t >= off && t < BROWS) ? incl[t - off] : 0;
        __syncthreads();
        if (t < BROWS) incl[t] += n;
        __syncthreads();
    }
    int ex = (t < BROWS) ? (incl[t] - v) : 0;
    __syncthreads();
    if (t < BROWS) hist[t] = ex;          // cursor init
    int gr = b * BROWS + t;
    if (t < BROWS && gr < N_NODES) row_ptr[gr] = base + ex;
    if (b == 0 && t == 0) row_ptr[N_NODES] = N_EDGES;
    __syncthreads();
    for (int i = t; i < cnt; i += 1024) {
        int2 e = eds[i];
        int l = (int)(((unsigned)e.x) >> 16) & (BROWS - 1);
        int p = atomicAdd(&hist[l], 1);
        unsigned col = (unsigned)e.x & 0xFFFFu;
        unsigned vb = (unsigned)__builtin_bit_cast(
            unsigned short, (_Float16)__int_as_float(e.y));
        csr4[base + p] = (col << 16) | vb;
    }
}

// f16x2 dot-product-accumulate: D = a.lo*b.lo + a.hi*b.hi + c (f32 accum)
__device__ inline float fdot2(unsigned a, unsigned b, float c) {
    return __builtin_amdgcn_fdot2(__builtin_bit_cast(half2v, a),
                                  __builtin_bit_cast(half2v, b), c, false);
}

// two edges (ra,ua) and (rb,ub): 1 val-perm + 8 feat-perms + 8 dot2.
// perm(x, y, SEL_LO) -> half2(lo = x.lo16, hi = y.lo16).
// vp = (va, vb); fp = (ua.fK, ub.fK); dot2 -> va*ua.fK + vb*ub.fK.
__device__ inline void dot8pair(unsigned ra, unsigned rb, uint4 ua, uint4 ub,
                                float4& accL, float4& accH) {
    unsigned vp = __builtin_amdgcn_perm(ra, rb, SEL_LO);
    accL.x = fdot2(vp, __builtin_amdgcn_perm(ua.x, ub.x, SEL_LO), accL.x);
    accL.y = fdot2(vp, __builtin_amdgcn_perm(ua.x, ub.x, SEL_HI), accL.y);
    accL.z = fdot2(vp, __builtin_amdgcn_perm(ua.y, ub.y, SEL_LO), accL.z);
    accL.w = fdot2(vp, __builtin_amdgcn_perm(ua.y, ub.y, SEL_HI), accL.w);
    accH.x = fdot2(vp, __builtin_amdgcn_perm(ua.z, ub.z, SEL_LO), accH.x);
    accH.y = fdot2(vp, __builtin_amdgcn_perm(ua.z, ub.z, SEL_HI), accH.y);
    accH.z = fdot2(vp, __builtin_amdgcn_perm(ua.w, ub.w, SEL_LO), accH.z);
    accH.w = fdot2(vp, __builtin_amdgcn_perm(ua.w, ub.w, SEL_HI), accH.w);
}

// unpack 8 f16 (uint4) -> 2x float4 (epilogue only)
__device__ inline void up8h(uint4 u, float4& lo, float4& hi) {
    half2v a = __builtin_bit_cast(half2v, u.x);
    half2v b = __builtin_bit_cast(half2v, u.y);
    half2v cc = __builtin_bit_cast(half2v, u.z);
    half2v dd = __builtin_bit_cast(half2v, u.w);
    lo.x = (float)a.x; lo.y = (float)a.y; lo.z = (float)b.x; lo.w = (float)b.y;
    hi.x = (float)cc.x; hi.y = (float)cc.y; hi.z = (float)dd.x; hi.w = (float)dd.y;
}

// SpMM quad-gather: 4 edge-slots x 16 lanes (r1 geometry, 8 edges/iter,
// 2 gathers in flight). Math: f16 perm+fdot2 edge-pairs (17 VALU / 2 edges
// vs 34 for unpack+FMA). rec = col<<16 | f16(val). Pad recs = 0 (safe).
__global__ void spmm_fused(const int* __restrict__ row_ptr,
                           const unsigned* __restrict__ csr4,
                           const uint4* __restrict__ xb,
                           uint4* __restrict__ yb,
                           float* __restrict__ norm_out,
                           const float* __restrict__ a,
                           const uint4* __restrict__ ep0,
                           const uint4* __restrict__ ep1,
                           const float* __restrict__ norms,
                           float* __restrict__ out,
                           int final_layer) {
    int wave = blockIdx.x * (blockDim.x >> 6) + (threadIdx.x >> 6);
    int lane = threadIdx.x & 63;
    if (wave >= N_NODES) return;
    int start = row_ptr[wave];
    int end   = row_ptr[wave + 1];
    int deg   = end - start;
    unsigned myrec = (lane < deg) ? csr4[start + lane] : 0u;
    int g = lane >> 4, c = lane & 15;
    float4 accL = make_float4(0.0f, 0.0f, 0.0f, 0.0f);
    float4 accH = make_float4(0.0f, 0.0f, 0.0f, 0.0f);
    int dn  = (deg < 64) ? deg : 64;
    int dn8 = (dn + 7) & ~7;           // round up to 8 (pad recs are 0)
    for (int d = 0; d < dn8; d += 8) { // 2 gathers in flight : 8 edges
        unsigned ra = __shfl(myrec, d + g);
        unsigned rb = __shfl(myrec, d + 4 + g);
        uint4 ua = xb[(size_t)(ra >> 16) * ROW_U4 + c];
        uint4 ub = xb[(size_t)(rb >> 16) * ROW_U4 + c];
        dot8pair(ra, rb, ua, ub, accL, accH);
    }
    // overflow fallback (deg > 64): edge pairs (e+g, e+4+g), guarded
    for (int e = start + 64; e < end; e += 8) {
        unsigned ra = (e + g < end) ? csr4[e + g] : 0u;
        unsigned rb = (e + 4 + g < end) ? csr4[e + 4 + g] : 0u;
        uint4 ua = xb[(size_t)(ra >> 16) * ROW_U4 + c];
        uint4 ub = xb[(size_t)(rb >> 16) * ROW_U4 + c];
        dot8pair(ra, rb, ua, ub, accL, accH);
    }
    // combine the 4 edge-slot groups: after this all 4 groups hold full sums
    accL.x += __shfl_xor(accL.x, 16); accL.x += __shfl_xor(accL.x, 32);
    accL.y += __shfl_xor(accL.y, 16); accL.y += __shfl_xor(accL.y, 32);
    accL.z += __shfl_xor(accL.z, 16); accL.z += __shfl_xor(accL.z, 32);
    accL.w += __shfl_xor(accL.w, 16); accL.w += __shfl_xor(accL.w, 32);
    accH.x += __shfl_xor(accH.x, 16); accH.x += __shfl_xor(accH.x, 32);
    accH.y += __shfl_xor(accH.y, 16); accH.y += __shfl_xor(accH.y, 32);
    accH.z += __shfl_xor(accH.z, 16); accH.z += __shfl_xor(accH.z, 32);
    accH.w += __shfl_xor(accH.w, 16); accH.w += __shfl_xor(accH.w, 32);
    // norm: sum of squares over the 16 c-lanes of a group (groups duplicate)
    float s = accL.x * accL.x + accL.y * accL.y + accL.z * accL.z + accL.w * accL.w
            + accH.x * accH.x + accH.y * accH.y + accH.z * accH.z + accH.w * accH.w;
    s += __shfl_xor(s, 1); s += __shfl_xor(s, 2);
    s += __shfl_xor(s, 4); s += __shfl_xor(s, 8);
    if (!final_layer) {
        if (g == 0) {                  // 16 lanes write the full 256B padded row
            uint4 o;
            o.x = pack2h(accL.x, accL.y);
            o.y = pack2h(accL.z, accL.w);
            o.z = pack2h(accH.x, accH.y);
            o.w = pack2h(accH.z, accH.w);
            yb[(size_t)wave * ROW_U4 + c] = o;   // c>=13 lanes hold exact zeros
        }
        if (lane == 0) norm_out[wave] = sqrtf(s);
    } else {
        float s0 = a[0] / fmaxf(norms[wave], NORM_EPS);
        float s1 = a[1] / fmaxf(norms[N_NODES + wave], NORM_EPS);
        float s2 = a[2] / fmaxf(norms[2 * N_NODES + wave], NORM_EPS);
        float s3 = a[3] / fmaxf(sqrtf(s), NORM_EPS);
        if (g == 0 && c < 13) {
            size_t idx = (size_t)wave * ROW_U4 + c;
            float4 f0l, f0h, f1l, f1h, f2l, f2h;
            up8h(ep0[idx], f0l, f0h);  // f16(emb)
            up8h(ep1[idx], f1l, f1h);  // x1
            up8h(xb[idx],  f2l, f2h);  // x2 (the gather table, L2-warm)
            float4 o0, o1;
            o0.x = s0 * f0l.x + s1 * f1l.x + s2 * f2l.x + s3 * accL.x;
            o0.y = s0 * f0l.y + s1 * f1l.y + s2 * f2l.y + s3 * accL.y;
            o0.z = s0 * f0l.z + s1 * f1l.z + s2 * f2l.z + s3 * accL.z;
            o0.w = s0 * f0l.w + s1 * f1l.w + s2 * f2l.w + s3 * accL.w;
            o1.x = s0 * f0h.x + s1 * f1h.x + s2 * f2h.x + s3 * accH.x;
            o1.y = s0 * f0h.y + s1 * f1h.y + s2 * f2h.y + s3 * accH.y;
            o1.z = s0 * f0h.z + s1 * f1h.z + s2 * f2h.z + s3 * accH.z;
            o1.w = s0 * f0h.w + s1 * f1h.w + s2 * f2h.w + s3 * accH.w;
            float4* out4 = (float4*)out;
            size_t fb = (size_t)wave * 25;       // out rows are unpadded f32x100
            if (c < 12) {
                out4[fb + 2 * c]     = o0;
                out4[fb + 2 * c + 1] = o1;
            } else {                   // c==12: feats 96..99 only
                out4[fb + 24] = o0;
            }
        }
    }
}

extern "C" void kernel_launch(void* const* d_in, const int* in_sizes, int n_in,
                              void* d_out, int out_size, void* d_ws, size_t ws_size,
                              hipStream_t stream) {
    const int*   adj_row   = (const int*)d_in[0];
    const int*   adj_col   = (const int*)d_in[1];
    const float* adj_val   = (const float*)d_in[2];
    const float* embedding = (const float*)d_in[3];
    const float* a         = (const float*)d_in[4];
    float* out = (float*)d_out;

    // workspace layout. xb2 overlays slab (slab dead after csr_build,
    // xb2 first written in layer-2 spmm -- stream-ordered, safe).
    // padded tables: 50000 * 16 uint4 = 12.8 MB each; slab = 12,812,288 B >= xb2.
    int2* slab     = (int2*)d_ws;                                  // 12.81 MB
    unsigned* csr4 = (unsigned*)(slab + (size_t)NB * CAP);         // 3.2 MB
    uint4* xbE = (uint4*)(csr4 + N_EDGES);                         // 12.8 MB
    uint4* xb1 = xbE + (size_t)N_NODES * ROW_U4;                   // 12.8 MB
    float* norms = (float*)(xb1 + (size_t)N_NODES * ROW_U4);       // 3*50,000
    int* row_ptr    = (int*)(norms + 3 * N_NODES);                 // 50,001
    int* bucket_cnt = row_ptr + (N_NODES + 1);                     // NB
    uint4* xb2 = (uint4*)slab;                                     // overlay

    const int node_blocks = (N_NODES + 3) / 4;          // 4 waves / block

    // ---- CSR build: (scatter || emb prep) -> per-bucket sort ----
    hipMemsetAsync(bucket_cnt, 0, sizeof(int) * NB, stream);
    scatter_conv<<<SCAT_BLOCKS + CONV_BLOCKS, 1024, 0, stream>>>(
        adj_row, adj_col, adj_val, bucket_cnt, slab,
        embedding, norms, (unsigned*)xbE);
    csr_build<<<NB, 1024, 0, stream>>>(bucket_cnt, slab, csr4, row_ptr);

    // ---- layer 1, 2 (raw f16 + norm), layer 3 (fused epilogue) ----
    spmm_fused<<<node_blocks, 256, 0, stream>>>(row_ptr, csr4, xbE,
                                                xb1, norms + N_NODES, a,
                                                nullptr, nullptr, nullptr,
                                                nullptr, 0);
    spmm_fused<<<node_blocks, 256, 0, stream>>>(row_ptr, csr4, xb1,
                                                xb2, norms + 2 * N_NODES, a,
                                                nullptr, nullptr, nullptr,
                                                nullptr, 0);
    spmm_fused<<<node_blocks, 256, 0, stream>>>(row_ptr, csr4, xb2,
                                                nullptr, nullptr, a,
                                                xbE, xb1, norms,
                                                out, 1);
}

// Round 9
// 195.358 us; speedup vs baseline: 1.1653x; 1.0392x over previous
//
#include <hip/hip_runtime.h>
#include <hip/hip_bf16.h>

#define N_NODES 50000
#define N_EDGES 800000
#define EMB 100
#define HALF_EMB 50
#define ROW_U4 16                      // uint4 per padded row (128 bf16, 256B = 4 cachelines)
#define ROW_B2 64                      // bf162 per padded row
#define NORM_EPS 1e-12f
#define BROWS 128                      // rows per bucket
#define NB ((N_NODES + BROWS - 1) / BROWS)   // 391 buckets
#define CAP 4096                       // slab capacity per bucket (avg fill ~2046)
#define EPB 4096                       // edges per partition block -> run len ~10.5
#define SCAT_BLOCKS ((N_EDGES + EPB - 1) / EPB)   // 196
#define CONV_BLOCKS 3125               // 16 waves x 3125 = 50000 nodes exactly

// Dispatch A (merged): blocks [0,196) = bucket scatter (1024 thr, 16 waves for
// latency hiding); blocks [196, 196+3125) = conv_emb. Disjoint inputs -> the
// conv blocks use the CUs scatter leaves idle.  [r1-exact, 28.6us]
__global__ __launch_bounds__(1024) void scatter_conv(
        const int* __restrict__ adj_row, const int* __restrict__ adj_col,
        const float* __restrict__ adj_val, int* __restrict__ bucket_cnt,
        int2* __restrict__ slab,
        const float* __restrict__ emb, float* __restrict__ norm0,
        __hip_bfloat162* __restrict__ xb) {
    const int t = threadIdx.x;
    if (blockIdx.x >= SCAT_BLOCKS) {
        // ---- conv_emb: one wave per node, writes 256B padded bf16 row ----
        int wave = (blockIdx.x - SCAT_BLOCKS) * 16 + (t >> 6);
        int lane = t & 63;
        if (wave >= N_NODES) return;
        float2 v = make_float2(0.0f, 0.0f);
        if (lane < HALF_EMB) v = ((const float2*)emb)[(size_t)wave * HALF_EMB + lane];
        float s = v.x * v.x + v.y * v.y;
        #pragma unroll
        for (int off = 32; off > 0; off >>= 1) s += __shfl_xor(s, off);
        if (lane == 0) norm0[wave] = sqrtf(s);
        __hip_bfloat162 b;
        b.x = __float2bfloat16(v.x);     // lanes >= 50 write exact zeros (pad)
        b.y = __float2bfloat16(v.y);
        xb[(size_t)wave * ROW_B2 + lane] = b;   // all 64 lanes: 256B coalesced
        return;
    }
    // ---- bucket scatter ----
    __shared__ int hist[NB];
    __shared__ int cur[NB];
    const int base_e = blockIdx.x * EPB;
    for (int i = t; i < NB; i += 1024) hist[i] = 0;
    __syncthreads();
    int rows[EPB / 1024];
    #pragma unroll
    for (int j = 0; j < EPB / 1024; ++j) {
        int e = base_e + j * 1024 + t;
        int r = (e < N_EDGES) ? adj_row[e] : -1;
        rows[j] = r;
        if (r >= 0) atomicAdd(&hist[r >> 7], 1);
    }
    __syncthreads();
    for (int i = t; i < NB; i += 1024) {
        int c = hist[i];
        cur[i] = (c > 0) ? atomicAdd(&bucket_cnt[i], c) : 0;
    }
    __syncthreads();
    #pragma unroll
    for (int j = 0; j < EPB / 1024; ++j) {
        int e = base_e + j * 1024 + t;
        int r = rows[j];
        if (r >= 0) {
            int b = r >> 7;
            int p = atomicAdd(&cur[b], 1);
            unsigned rc = ((unsigned)r << 16) | (unsigned)adj_col[e];
            slab[(size_t)b * CAP + p] = make_int2((int)rc, __float_as_int(adj_val[e]));
        }
    }
}

// Dispatch B: per-bucket counting sort (1024 thr) -> compressed CSR + row_ptr.
// v2 (correctness-proven in r3): no LDS edge staging (slab is L2-hot, re-read
// on pass 2); wave-shfl reduce for bucket prefix; 2-wave shfl scan for the
// 128 bins. 4 barriers vs 24, LDS 38KB -> ~1KB.
__global__ __launch_bounds__(1024) void csr_build(
        const int* __restrict__ bucket_cnt, const int2* __restrict__ slab,
        unsigned* __restrict__ csr4, int* __restrict__ row_ptr) {
    __shared__ int hist[BROWS];   // histogram, then scatter cursor
    __shared__ int wsum[16];
    __shared__ int wtot[2];
    __shared__ int base_sh;
    const int b = blockIdx.x, t = threadIdx.x;
    const int lane = t & 63, wid = t >> 6;
    // base = sum_{i<b} bucket_cnt[i]  (b < 391 < 1024): wave reduce
    int pv = (t < b) ? bucket_cnt[t] : 0;
    #pragma unroll
    for (int off = 32; off > 0; off >>= 1) pv += __shfl_xor(pv, off);
    if (lane == 0) wsum[wid] = pv;
    if (t < BROWS) hist[t] = 0;
    const int cnt = bucket_cnt[b];
    __syncthreads();                       // wsum ready, hist zeroed
    if (t == 0) {
        int s_ = 0;
        #pragma unroll
        for (int i = 0; i < 16; ++i) s_ += wsum[i];
        base_sh = s_;
    }
    // pass 1: histogram straight from global (L2-hot slab)
    for (int i = t; i < cnt; i += 1024)
        atomicAdd(&hist[(int)(((unsigned)slab[(size_t)b * CAP + i].x) >> 16) & (BROWS - 1)], 1);
    __syncthreads();                       // hist complete, base_sh visible
    const int base = base_sh;
    // exclusive scan of 128 bins: 2-wave in-register shfl scan
    int v = (t < BROWS) ? hist[t] : 0;
    int sc = v;
    #pragma unroll
    for (int off = 1; off < 64; off <<= 1) {
        int n = __shfl_up(sc, off);
        if (lane >= off) sc += n;
    }
    if (t < BROWS && lane == 63) wtot[wid] = sc;
    __syncthreads();
    if (wid == 1 && t < BROWS) sc += wtot[0];
    int ex = sc - v;
    if (t < BROWS) {
        hist[t] = ex;                      // cursor init
        int gr = b * BROWS + t;
        if (gr < N_NODES) row_ptr[gr] = base + ex;
    }
    if (b == 0 && t == 0) row_ptr[N_NODES] = N_EDGES;
    __syncthreads();
    // pass 2: scatter (re-read slab), compress to col<<16 | bf16(val)
    for (int i = t; i < cnt; i += 1024) {
        int2 e = slab[(size_t)b * CAP + i];
        int l = (int)(((unsigned)e.x) >> 16) & (BROWS - 1);
        int p = atomicAdd(&hist[l], 1);
        unsigned col = (unsigned)e.x & 0xFFFFu;
        __hip_bfloat16 hv = __float2bfloat16(__int_as_float(e.y));
        unsigned vb = (unsigned)*reinterpret_cast<unsigned short*>(&hv);
        csr4[base + p] = (col << 16) | vb;
    }
}

// unpack 8 bf16 (uint4) -> 2x float4, bit-twiddle only
__device__ inline void up8(uint4 u, float4& lo, float4& hi) {
    lo.x = __uint_as_float(u.x << 16);
    lo.y = __uint_as_float(u.x & 0xFFFF0000u);
    lo.z = __uint_as_float(u.y << 16);
    lo.w = __uint_as_float(u.y & 0xFFFF0000u);
    hi.x = __uint_as_float(u.z << 16);
    hi.y = __uint_as_float(u.z & 0xFFFF0000u);
    hi.z = __uint_as_float(u.w << 16);
    hi.w = __uint_as_float(u.w & 0xFFFF0000u);
}

__device__ inline unsigned pack2(float a, float b) {
    __hip_bfloat16 x = __float2bfloat16(a), y = __float2bfloat16(b);
    return (unsigned)*(unsigned short*)&x | ((unsigned)*(unsigned short*)&y << 16);
}

// SpMM quad-gather [r1-exact, ~35us/layer]: 4 edge-slots x 16 lanes. Slot
// g = lane>>4 owns edge d+g; lane (g,c) loads uint4 = 8 bf16 features of its
// edge's source row (padded 256B rows -> all 64 lanes active, 16B/lane).
// Records broadcast with a divergent-source shfl. Pad recs = 0 (safe).
// rec = col<<16 | bf16(val): col = rec>>16, val = bits(rec<<16) (exact).
__global__ void spmm_fused(const int* __restrict__ row_ptr,
                           const unsigned* __restrict__ csr4,
                           const uint4* __restrict__ xb,
                           uint4* __restrict__ yb,
                           float* __restrict__ norm_out,
                           const float* __restrict__ a,
                           const uint4* __restrict__ ep0,
                           const uint4* __restrict__ ep1,
                           const float* __restrict__ norms,
                           float* __restrict__ out,
                           int final_layer) {
    int wave = blockIdx.x * (blockDim.x >> 6) + (threadIdx.x >> 6);
    int lane = threadIdx.x & 63;
    if (wave >= N_NODES) return;
    int start = row_ptr[wave];
    int end   = row_ptr[wave + 1];
    int deg   = end - start;
    unsigned myrec = (lane < deg) ? csr4[start + lane] : 0u;
    int g = lane >> 4, c = lane & 15;
    float4 accL = make_float4(0.0f, 0.0f, 0.0f, 0.0f);
    float4 accH = make_float4(0.0f, 0.0f, 0.0f, 0.0f);
    int dn  = (deg < 64) ? deg : 64;
    int dn4 = (dn + 3) & ~3;           // round up to quads (pad recs are 0)
    int d = 0;
    for (; d + 8 <= dn4; d += 8) {     // 2 gathers in flight : 8 edges
        unsigned ra = __shfl(myrec, d + g);
        unsigned rb = __shfl(myrec, d + 4 + g);
        uint4 ua = xb[(size_t)(ra >> 16) * ROW_U4 + c];
        uint4 ub = xb[(size_t)(rb >> 16) * ROW_U4 + c];
        float va = __uint_as_float(ra << 16);
        float vb = __uint_as_float(rb << 16);
        float4 l, h;
        up8(ua, l, h);
        accL.x += va * l.x; accL.y += va * l.y; accL.z += va * l.z; accL.w += va * l.w;
        accH.x += va * h.x; accH.y += va * h.y; accH.z += va * h.z; accH.w += va * h.w;
        up8(ub, l, h);
        accL.x += vb * l.x; accL.y += vb * l.y; accL.z += vb * l.z; accL.w += vb * l.w;
        accH.x += vb * h.x; accH.y += vb * h.y; accH.z += vb * h.z; accH.w += vb * h.w;
    }
    for (; d < dn4; d += 4) {
        unsigned r = __shfl(myrec, d + g);
        uint4 u = xb[(size_t)(r >> 16) * ROW_U4 + c];
        float v = __uint_as_float(r << 16);
        float4 l, h;
        up8(u, l, h);
        accL.x += v * l.x; accL.y += v * l.y; accL.z += v * l.z; accL.w += v * l.w;
        accH.x += v * h.x; accH.y += v * h.y; accH.z += v * h.z; accH.w += v * h.w;
    }
    // overflow fallback (deg > 64): quads, slot g selects edge
    for (int e = start + 64; e < end; e += 4) {
        unsigned r = (e + g < end) ? csr4[e + g] : 0u;
        uint4 u = xb[(size_t)(r >> 16) * ROW_U4 + c];
        float v = __uint_as_float(r << 16);
        float4 l, h;
        up8(u, l, h);
        accL.x += v * l.x; accL.y += v * l.y; accL.z += v * l.z; accL.w += v * l.w;
        accH.x += v * h.x; accH.y += v * h.y; accH.z += v * h.z; accH.w += v * h.w;
    }
    // combine the 4 edge-slot groups: after this all 4 groups hold full sums
    accL.x += __shfl_xor(accL.x, 16); accL.x += __shfl_xor(accL.x, 32);
    accL.y += __shfl_xor(accL.y, 16); accL.y += __shfl_xor(accL.y, 32);
    accL.z += __shfl_xor(accL.z, 16); accL.z += __shfl_xor(accL.z, 32);
    accL.w += __shfl_xor(accL.w, 16); accL.w += __shfl_xor(accL.w, 32);
    accH.x += __shfl_xor(accH.x, 16); accH.x += __shfl_xor(accH.x, 32);
    accH.y += __shfl_xor(accH.y, 16); accH.y += __shfl_xor(accH.y, 32);
    accH.z += __shfl_xor(accH.z, 16); accH.z += __shfl_xor(accH.z, 32);
    accH.w += __shfl_xor(accH.w, 16); accH.w += __shfl_xor(accH.w, 32);
    // norm: sum of squares over the 16 c-lanes of a group (groups duplicate)
    float s = accL.x * accL.x + accL.y * accL.y + accL.z * accL.z + accL.w * accL.w
            + accH.x * accH.x + accH.y * accH.y + accH.z * accH.z + accH.w * accH.w;
    s += __shfl_xor(s, 1); s += __shfl_xor(s, 2);
    s += __shfl_xor(s, 4); s += __shfl_xor(s, 8);
    if (!final_layer) {
        if (g == 0) {                  // 16 lanes write the full 256B padded row
            uint4 o;
            o.x = pack2(accL.x, accL.y);
            o.y = pack2(accL.z, accL.w);
            o.z = pack2(accH.x, accH.y);
            o.w = pack2(accH.z, accH.w);
            yb[(size_t)wave * ROW_U4 + c] = o;   // c>=13 lanes hold exact zeros
        }
        if (lane == 0) norm_out[wave] = sqrtf(s);
    } else {
        float s0 = a[0] / fmaxf(norms[wave], NORM_EPS);
        float s1 = a[1] / fmaxf(norms[N_NODES + wave], NORM_EPS);
        float s2 = a[2] / fmaxf(norms[2 * N_NODES + wave], NORM_EPS);
        float s3 = a[3] / fmaxf(sqrtf(s), NORM_EPS);
        if (g == 0 && c < 13) {
            size_t idx = (size_t)wave * ROW_U4 + c;
            float4 f0l, f0h, f1l, f1h, f2l, f2h;
            up8(ep0[idx], f0l, f0h);   // bf16(emb)
            up8(ep1[idx], f1l, f1h);   // x1
            up8(xb[idx],  f2l, f2h);   // x2 (the gather table, L2-warm)
            float4 o0, o1;
            o0.x = s0 * f0l.x + s1 * f1l.x + s2 * f2l.x + s3 * accL.x;
            o0.y = s0 * f0l.y + s1 * f1l.y + s2 * f2l.y + s3 * accL.y;
            o0.z = s0 * f0l.z + s1 * f1l.z + s2 * f2l.z + s3 * accL.z;
            o0.w = s0 * f0l.w + s1 * f1l.w + s2 * f2l.w + s3 * accL.w;
            o1.x = s0 * f0h.x + s1 * f1h.x + s2 * f2h.x + s3 * accH.x;
            o1.y = s0 * f0h.y + s1 * f1h.y + s2 * f2h.y + s3 * accH.y;
            o1.z = s0 * f0h.z + s1 * f1h.z + s2 * f2h.z + s3 * accH.z;
            o1.w = s0 * f0h.w + s1 * f1h.w + s2 * f2h.w + s3 * accH.w;
            float4* out4 = (float4*)out;
            size_t fb = (size_t)wave * 25;       // out rows are unpadded f32x100
            if (c < 12) {
                out4[fb + 2 * c]     = o0;
                out4[fb + 2 * c + 1] = o1;
            } else {                   // c==12: feats 96..99 only
                out4[fb + 24] = o0;
            }
        }
    }
}

extern "C" void kernel_launch(void* const* d_in, const int* in_sizes, int n_in,
                              void* d_out, int out_size, void* d_ws, size_t ws_size,
                              hipStream_t stream) {
    const int*   adj_row   = (const int*)d_in[0];
    const int*   adj_col   = (const int*)d_in[1];
    const float* adj_val   = (const float*)d_in[2];
    const float* embedding = (const float*)d_in[3];
    const float* a         = (const float*)d_in[4];
    float* out = (float*)d_out;

    // workspace layout. xb2 overlays slab (slab dead after csr_build,
    // xb2 first written in layer-2 spmm -- stream-ordered, safe).
    // padded tables: 50000 * 16 uint4 = 12.8 MB each; slab = 12,812,288 B >= xb2.
    int2* slab     = (int2*)d_ws;                                  // 12.81 MB
    unsigned* csr4 = (unsigned*)(slab + (size_t)NB * CAP);         // 3.2 MB
    uint4* xbE = (uint4*)(csr4 + N_EDGES);                         // 12.8 MB
    uint4* xb1 = xbE + (size_t)N_NODES * ROW_U4;                   // 12.8 MB
    float* norms = (float*)(xb1 + (size_t)N_NODES * ROW_U4);       // 3*50,000
    int* row_ptr    = (int*)(norms + 3 * N_NODES);                 // 50,001
    int* bucket_cnt = row_ptr + (N_NODES + 1);                     // NB
    uint4* xb2 = (uint4*)slab;                                     // overlay

    const int node_blocks = (N_NODES + 3) / 4;          // 4 waves / block

    // ---- CSR build: (scatter || emb prep) -> per-bucket sort ----
    hipMemsetAsync(bucket_cnt, 0, sizeof(int) * NB, stream);
    scatter_conv<<<SCAT_BLOCKS + CONV_BLOCKS, 1024, 0, stream>>>(
        adj_row, adj_col, adj_val, bucket_cnt, slab,
        embedding, norms, (__hip_bfloat162*)xbE);
    csr_build<<<NB, 1024, 0, stream>>>(bucket_cnt, slab, csr4, row_ptr);

    // ---- layer 1, 2 (raw bf16 + norm), layer 3 (fused epilogue) ----
    spmm_fused<<<node_blocks, 256, 0, stream>>>(row_ptr, csr4, xbE,
                                                xb1, norms + N_NODES, a,
                                                nullptr, nullptr, nullptr,
                                                nullptr, 0);
    spmm_fused<<<node_blocks, 256, 0, stream>>>(row_ptr, csr4, xb1,
                                                xb2, norms + 2 * N_NODES, a,
                                                nullptr, nullptr, nullptr,
                                                nullptr, 0);
    spmm_fused<<<node_blocks, 256, 0, stream>>>(row_ptr, csr4, xb2,
                                                nullptr, nullptr, a,
                                                xbE, xb1, norms,
                                                out, 1);
}